// Round 7
// baseline (74.107 us; speedup 1.0000x reference)
//
#include <hip/hip_runtime.h>
#include <hip/hip_bf16.h>
#include <math.h>

#define NP 16
#define NB 512
#define ND 2048
#define NM (NP*NB)          // 8192 rows
#define BK 32
#define NS (ND/BK)          // 64 K-steps

typedef __attribute__((ext_vector_type(8))) short bf16x8;
typedef __attribute__((ext_vector_type(4))) float f32x4;
typedef unsigned int u32;

__device__ inline unsigned short f2bf(float f) {
    unsigned u = __float_as_uint(f);
    unsigned r = (u + 0x7fffu + ((u >> 16) & 1u)) >> 16;   // RNE
    return (unsigned short)r;
}

__device__ inline float dot4(float4 v) {
    return v.x * v.x + v.y * v.y + v.z * v.z + v.w * v.w;
}

// ---------------------------------------------------------------------------
// Prep: one pass over feat -> row-normalized bf16 A + normalized bf16 z row.
__global__ __launch_bounds__(256) void prep_kernel(
        const float* __restrict__ feat,
        unsigned short* __restrict__ an,     // [NM][ND] bf16, row-normalized
        unsigned short* __restrict__ zn) {   // [NB][ND] bf16, row-normalized
    const int b = blockIdx.x, tid = threadIdx.x;
    const int lane = tid & 63, wv = tid >> 6;
    const float4* feat4 = (const float4*)feat;

    float4 zp[8];
#pragma unroll
    for (int it = 0; it < 8; ++it) zp[it] = make_float4(0.f, 0.f, 0.f, 0.f);

#pragma unroll
    for (int j = 0; j < 4; ++j) {
        const int p = wv * 4 + j;
        const size_t row = (size_t)p * NB + b;
        const float4* rp = feat4 + row * (ND / 4);
        float4 rv[8];
        float ss = 0.f;
#pragma unroll
        for (int it = 0; it < 8; ++it) {
            rv[it] = rp[it * 64 + lane];
            ss += dot4(rv[it]);
            zp[it].x += rv[it].x; zp[it].y += rv[it].y;
            zp[it].z += rv[it].z; zp[it].w += rv[it].w;
        }
#pragma unroll
        for (int off = 32; off > 0; off >>= 1) ss += __shfl_xor(ss, off);
        const float inv = 1.f / fmaxf(sqrtf(ss), 1e-12f);
        ushort4* wp = (ushort4*)(an + row * ND);
#pragma unroll
        for (int it = 0; it < 8; ++it) {
            ushort4 o;
            o.x = f2bf(rv[it].x * inv); o.y = f2bf(rv[it].y * inv);
            o.z = f2bf(rv[it].z * inv); o.w = f2bf(rv[it].w * inv);
            wp[it * 64 + lane] = o;
        }
    }

    __shared__ float4 zl[4][512];        // 32 KB
#pragma unroll
    for (int it = 0; it < 8; ++it) zl[wv][it * 64 + lane] = zp[it];
    __syncthreads();

    float4 z0 = zl[0][tid];
    float4 z1 = zl[0][tid + 256];
    {
        float4 a = zl[1][tid], c = zl[2][tid], d = zl[3][tid];
        z0.x += a.x + c.x + d.x; z0.y += a.y + c.y + d.y;
        z0.z += a.z + c.z + d.z; z0.w += a.w + c.w + d.w;
        float4 e = zl[1][tid + 256], f = zl[2][tid + 256], g = zl[3][tid + 256];
        z1.x += e.x + f.x + g.x; z1.y += e.y + f.y + g.y;
        z1.z += e.z + f.z + g.z; z1.w += e.w + f.w + g.w;
    }
    float ss = dot4(z0) + dot4(z1);
#pragma unroll
    for (int off = 32; off > 0; off >>= 1) ss += __shfl_xor(ss, off);
    __shared__ float wpart[4];
    __shared__ float invz_s;
    if (lane == 0) wpart[wv] = ss;
    __syncthreads();
    if (tid == 0)
        invz_s = 1.f / fmaxf(sqrtf(wpart[0] + wpart[1] + wpart[2] + wpart[3]), 1e-12f);
    __syncthreads();
    const float iz = invz_s;
    ushort4 o0, o1;
    o0.x = f2bf(z0.x * iz); o0.y = f2bf(z0.y * iz);
    o0.z = f2bf(z0.z * iz); o0.w = f2bf(z0.w * iz);
    o1.x = f2bf(z1.x * iz); o1.y = f2bf(z1.y * iz);
    o1.z = f2bf(z1.z * iz); o1.w = f2bf(z1.w * iz);
    ((ushort4*)(zn + (size_t)b * ND))[tid] = o0;
    ((ushort4*)(zn + (size_t)b * ND))[tid + 256] = o1;
}

// ---------------------------------------------------------------------------
// GEMM + fused CE loss. Block = 32 rows x 512 cols, 1024 thr = 16 waves.
// BK=32, FOUR LDS buffers, 3-deep global_load_lds staging, ONE barrier per
// step. Overwrite safety: per-wave lgkmcnt(0) precedes stage-issue in each
// step, and the top-of-step barrier orders it against all other waves.
// Swizzle involution cs = c ^ ((r>>1)&3) on BOTH global source and LDS reads
// (linear LDS dest for global_load_lds) -> 2-way banks on reads (free).
__global__ __launch_bounds__(1024, 4) void gemm_loss_kernel(
        const unsigned short* __restrict__ an, // [NM][ND] bf16
        const unsigned short* __restrict__ zn, // [NB][ND] bf16
        float* __restrict__ loss_acc) {
    __shared__ __align__(16) unsigned char bbuf[4][NB * BK * 2];   // 4 x 32 KB
    __shared__ __align__(16) unsigned char abuf[4][32 * BK * 2];   // 4 x 2 KB
    __shared__ float sm_max[32][16];
    __shared__ float sm_sum[32][16];
    __shared__ float sm_pos[32];

    const int tid  = threadIdx.x;
    const int lane = tid & 63;
    const int w    = tid >> 6;       // 0..15
    const int l15  = lane & 15;
    const int l4   = lane >> 4;      // 0..3
    const int brow = blockIdx.x * 32;
    const bool a_wave = (tid < 128); // waves 0,1 also stage A (3 loads/stage)

    const unsigned char* znb = (const unsigned char*)zn;
    const unsigned char* anb = (const unsigned char*)an;

    f32x4 acc[2][2] = {};

#define STAGE(buf, s) do {                                                    \
        const int koB = (s) * (BK * 2);  /* 64 B per row per step */          \
        _Pragma("unroll")                                                     \
        for (int i = 0; i < 2; ++i) {                                         \
            int q = i * 1024 + tid;                                           \
            int r = q >> 2, c = q & 3;                                        \
            int cs = c ^ ((r >> 1) & 3);                                      \
            __builtin_amdgcn_global_load_lds(                                 \
                (const u32*)(znb + (size_t)r * (ND * 2) + koB + cs * 16),     \
                (u32*)(&bbuf[buf][q * 16]), 16, 0, 0);                        \
        }                                                                     \
        if (a_wave) {                                                         \
            int r = tid >> 2, c = tid & 3;                                    \
            int cs = c ^ ((r >> 1) & 3);                                      \
            __builtin_amdgcn_global_load_lds(                                 \
                (const u32*)(anb + (size_t)(brow + r) * (ND * 2) + koB + cs * 16), \
                (u32*)(&abuf[buf][tid * 16]), 16, 0, 0);                      \
        }                                                                     \
    } while (0)

    STAGE(0, 0);
    STAGE(1, 1);
    STAGE(2, 2);

    for (int s = 0; s < NS; ++s) {
        // counted wait: stage s done, stages s+1,s+2 stay in flight
        if (s + 2 < NS) {
            if (a_wave) asm volatile("s_waitcnt vmcnt(6)" ::: "memory");
            else        asm volatile("s_waitcnt vmcnt(4)" ::: "memory");
        } else if (s + 1 < NS) {
            if (a_wave) asm volatile("s_waitcnt vmcnt(3)" ::: "memory");
            else        asm volatile("s_waitcnt vmcnt(2)" ::: "memory");
        } else {
            asm volatile("s_waitcnt vmcnt(0)" ::: "memory");
        }
        __builtin_amdgcn_sched_barrier(0);
        __builtin_amdgcn_s_barrier();            // buf[s&3] staged; prev reads done

        const int buf = s & 3;
        bf16x8 afr[2], bfr[2];
#pragma unroll
        for (int m = 0; m < 2; ++m) {
            int r = m * 16 + l15;
            int cs = l4 ^ ((r >> 1) & 3);
            afr[m] = *(const bf16x8*)(&abuf[buf][r * 64 + cs * 16]);
        }
#pragma unroll
        for (int n = 0; n < 2; ++n) {
            int r = w * 32 + n * 16 + l15;
            int cs = l4 ^ ((r >> 1) & 3);
            bfr[n] = *(const bf16x8*)(&bbuf[buf][r * 64 + cs * 16]);
        }
        __builtin_amdgcn_sched_barrier(0);
        asm volatile("s_waitcnt lgkmcnt(0)" ::: "memory");  // my reads complete
        __builtin_amdgcn_sched_barrier(0);

        if (s + 3 < NS) STAGE((s + 3) & 3, s + 3);   // flies under MFMA + next wait

        __builtin_amdgcn_s_setprio(1);
#pragma unroll
        for (int m = 0; m < 2; ++m)
#pragma unroll
        for (int n = 0; n < 2; ++n)
            acc[m][n] = __builtin_amdgcn_mfma_f32_16x16x32_bf16(
                afr[m], bfr[n], acc[m][n], 0, 0, 0);
        __builtin_amdgcn_s_setprio(0);
    }
#undef STAGE

    // ---- epilogue: logits = acc * (1/TEMP); per-row logsumexp - pos ----
#pragma unroll
    for (int m = 0; m < 2; ++m) {
#pragma unroll
        for (int r = 0; r < 4; ++r) {
            const int row = m * 16 + l4 * 4 + r;        // local row 0..31
            float lg[2];
            float mx = -1e30f;
#pragma unroll
            for (int n = 0; n < 2; ++n) {
                lg[n] = acc[m][n][r] * 5.0f;            // /TEMP
                mx = fmaxf(mx, lg[n]);
            }
            mx = fmaxf(mx, __shfl_xor(mx, 1));
            mx = fmaxf(mx, __shfl_xor(mx, 2));
            mx = fmaxf(mx, __shfl_xor(mx, 4));
            mx = fmaxf(mx, __shfl_xor(mx, 8));
            float se = 0.f;
#pragma unroll
            for (int n = 0; n < 2; ++n) se += __expf(lg[n] - mx);
            se += __shfl_xor(se, 1);
            se += __shfl_xor(se, 2);
            se += __shfl_xor(se, 4);
            se += __shfl_xor(se, 8);
            if (l15 == 0) { sm_max[row][w] = mx; sm_sum[row][w] = se; }
            const int posc = (brow + row) & (NB - 1);   // global row % 512
#pragma unroll
            for (int n = 0; n < 2; ++n)
                if (w * 32 + n * 16 + l15 == posc) sm_pos[row] = lg[n];
        }
    }
    __syncthreads();

    if (tid < 32) {
        const int row = tid;
        float gm = -1e30f;
#pragma unroll
        for (int wv = 0; wv < 16; ++wv) gm = fmaxf(gm, sm_max[row][wv]);
        float tot = 0.f;
#pragma unroll
        for (int wv = 0; wv < 16; ++wv)
            tot += sm_sum[row][wv] * __expf(sm_max[row][wv] - gm);
        float term = gm + __logf(tot) - sm_pos[row];
        term += __shfl_xor(term, 16);
        term += __shfl_xor(term, 8);
        term += __shfl_xor(term, 4);
        term += __shfl_xor(term, 2);
        term += __shfl_xor(term, 1);
        if (tid == 0) atomicAdd(loss_acc, term);
    }
}

__global__ void finalize_kernel(const float* __restrict__ acc,
                                float* __restrict__ out) {
    out[0] = acc[0] * (1.0f / (float)NM);
}

extern "C" void kernel_launch(void* const* d_in, const int* in_sizes, int n_in,
                              void* d_out, int out_size, void* d_ws, size_t ws_size,
                              hipStream_t stream) {
    const float* feat = (const float*)d_in[0];

    unsigned short* an = (unsigned short*)d_ws;            // 8192*2048 bf16 = 32 MB
    unsigned short* zn = an + (size_t)NM * ND;             // 512*2048 bf16 = 2 MB
    float* lacc = (float*)(zn + (size_t)NB * ND);          // 1 float

    hipMemsetAsync(lacc, 0, sizeof(float), stream);

    prep_kernel<<<NB, 256, 0, stream>>>(feat, an, zn);
    gemm_loss_kernel<<<NM / 32, 1024, 0, stream>>>(an, zn, lacc);
    finalize_kernel<<<1, 1, 0, stream>>>(lacc, (float*)d_out);
}

// Round 8
// 58.650 us; speedup vs baseline: 1.2635x; 1.2635x over previous
//
#include <hip/hip_runtime.h>
#include <hip/hip_bf16.h>
#include <math.h>

#define NP 16
#define NB 512
#define ND 2048
#define NM (NP*NB)          // 8192 rows
#define BM 128
#define BN 128
#define BK 64
#define NS (ND/BK)          // 32 K-steps

typedef __attribute__((ext_vector_type(8))) short bf16x8;
typedef __attribute__((ext_vector_type(4))) float f32x4;
typedef unsigned int u32;

__device__ inline unsigned short f2bf(float f) {
    unsigned u = __float_as_uint(f);
    unsigned r = (u + 0x7fffu + ((u >> 16) & 1u)) >> 16;   // RNE
    return (unsigned short)r;
}

__device__ inline float dot4(float4 v) {
    return v.x * v.x + v.y * v.y + v.z * v.z + v.w * v.w;
}

// ---------------------------------------------------------------------------
// Prep: one pass over feat -> row-normalized bf16 A + normalized bf16 z row.
__global__ __launch_bounds__(256) void prep_kernel(
        const float* __restrict__ feat,
        unsigned short* __restrict__ an,     // [NM][ND] bf16, row-normalized
        unsigned short* __restrict__ zn) {   // [NB][ND] bf16, row-normalized
    const int b = blockIdx.x, tid = threadIdx.x;
    const int lane = tid & 63, wv = tid >> 6;
    const float4* feat4 = (const float4*)feat;

    float4 zp[8];
#pragma unroll
    for (int it = 0; it < 8; ++it) zp[it] = make_float4(0.f, 0.f, 0.f, 0.f);

#pragma unroll
    for (int j = 0; j < 4; ++j) {
        const int p = wv * 4 + j;
        const size_t row = (size_t)p * NB + b;
        const float4* rp = feat4 + row * (ND / 4);
        float4 rv[8];
        float ss = 0.f;
#pragma unroll
        for (int it = 0; it < 8; ++it) {
            rv[it] = rp[it * 64 + lane];
            ss += dot4(rv[it]);
            zp[it].x += rv[it].x; zp[it].y += rv[it].y;
            zp[it].z += rv[it].z; zp[it].w += rv[it].w;
        }
#pragma unroll
        for (int off = 32; off > 0; off >>= 1) ss += __shfl_xor(ss, off);
        const float inv = 1.f / fmaxf(sqrtf(ss), 1e-12f);
        ushort4* wp = (ushort4*)(an + row * ND);
#pragma unroll
        for (int it = 0; it < 8; ++it) {
            ushort4 o;
            o.x = f2bf(rv[it].x * inv); o.y = f2bf(rv[it].y * inv);
            o.z = f2bf(rv[it].z * inv); o.w = f2bf(rv[it].w * inv);
            wp[it * 64 + lane] = o;
        }
    }

    __shared__ float4 zl[4][512];        // 32 KB
#pragma unroll
    for (int it = 0; it < 8; ++it) zl[wv][it * 64 + lane] = zp[it];
    __syncthreads();

    float4 z0 = zl[0][tid];
    float4 z1 = zl[0][tid + 256];
    {
        float4 a = zl[1][tid], c = zl[2][tid], d = zl[3][tid];
        z0.x += a.x + c.x + d.x; z0.y += a.y + c.y + d.y;
        z0.z += a.z + c.z + d.z; z0.w += a.w + c.w + d.w;
        float4 e = zl[1][tid + 256], f = zl[2][tid + 256], g = zl[3][tid + 256];
        z1.x += e.x + f.x + g.x; z1.y += e.y + f.y + g.y;
        z1.z += e.z + f.z + g.z; z1.w += e.w + f.w + g.w;
    }
    float ss = dot4(z0) + dot4(z1);
#pragma unroll
    for (int off = 32; off > 0; off >>= 1) ss += __shfl_xor(ss, off);
    __shared__ float wpart[4];
    __shared__ float invz_s;
    if (lane == 0) wpart[wv] = ss;
    __syncthreads();
    if (tid == 0)
        invz_s = 1.f / fmaxf(sqrtf(wpart[0] + wpart[1] + wpart[2] + wpart[3]), 1e-12f);
    __syncthreads();
    const float iz = invz_s;
    ushort4 o0, o1;
    o0.x = f2bf(z0.x * iz); o0.y = f2bf(z0.y * iz);
    o0.z = f2bf(z0.z * iz); o0.w = f2bf(z0.w * iz);
    o1.x = f2bf(z1.x * iz); o1.y = f2bf(z1.y * iz);
    o1.z = f2bf(z1.z * iz); o1.w = f2bf(z1.w * iz);
    ((ushort4*)(zn + (size_t)b * ND))[tid] = o0;
    ((ushort4*)(zn + (size_t)b * ND))[tid + 256] = o1;
}

// ---------------------------------------------------------------------------
// GEMM + partial CE loss. Block = 128x128, 256 thr = 4 waves (2x2), wave tile
// 64x64 (acc[4][4]): 32 MFMA per 16 ds_read_b128 per step (2:1). BK=64,
// 3 LDS buffers, 2-deep global_load_lds staging, ONE barrier per step,
// counted vmcnt(8). Buffer-overwrite safety: STAGE(s+2) writes buf[(s+2)%3],
// whose readers (step s-1) completed before this step's barrier.
// Swizzle cs = c ^ (r&7) on global source + LDS read (linear LDS dest).
__global__ __launch_bounds__(256, 1) void gemm_loss_kernel(
        const unsigned short* __restrict__ an, // [NM][ND] bf16
        const unsigned short* __restrict__ zn, // [NB][ND] bf16
        float* __restrict__ pmax_g,            // [4][NM]
        float* __restrict__ psum_g,            // [4][NM]
        float* __restrict__ ppos_g) {          // [NM]
    __shared__ __align__(16) unsigned char bbuf[3][BN * BK * 2];   // 3 x 16 KB
    __shared__ __align__(16) unsigned char abuf[3][BM * BK * 2];   // 3 x 16 KB
    __shared__ float sm_max[BM][2];
    __shared__ float sm_sum[BM][2];
    __shared__ float sm_pos[BM];

    const int tid  = threadIdx.x;
    const int lane = tid & 63;
    const int w    = tid >> 6;       // 0..3
    const int wr   = w >> 1;         // row strip 0..1
    const int wc   = w & 1;          // col strip 0..1
    const int l15  = lane & 15;
    const int l4   = lane >> 4;      // 0..3
    const int cb   = blockIdx.x & 3;
    const int brow = (blockIdx.x >> 2) * BM;
    const int bcol = cb * BN;

    const unsigned char* znb = (const unsigned char*)zn;
    const unsigned char* anb = (const unsigned char*)an;

    f32x4 acc[4][4] = {};

#define STAGE(buf, s) do {                                                    \
        const int koB = (s) * (BK * 2);   /* 128 B per row per step */        \
        _Pragma("unroll")                                                     \
        for (int i = 0; i < 4; ++i) {                                         \
            int q = i * 256 + tid;        /* 0..1023 */                       \
            int r = q >> 3, c = q & 7;                                        \
            int cs = c ^ (r & 7);                                             \
            __builtin_amdgcn_global_load_lds(                                 \
                (const u32*)(znb + (size_t)(bcol + r) * (ND * 2) + koB + cs * 16), \
                (u32*)(&bbuf[buf][q * 16]), 16, 0, 0);                        \
        }                                                                     \
        _Pragma("unroll")                                                     \
        for (int i = 0; i < 4; ++i) {                                         \
            int q = i * 256 + tid;                                            \
            int r = q >> 3, c = q & 7;                                        \
            int cs = c ^ (r & 7);                                             \
            __builtin_amdgcn_global_load_lds(                                 \
                (const u32*)(anb + (size_t)(brow + r) * (ND * 2) + koB + cs * 16), \
                (u32*)(&abuf[buf][q * 16]), 16, 0, 0);                        \
        }                                                                     \
    } while (0)

    STAGE(0, 0);
    STAGE(1, 1);

    for (int s = 0; s < NS; ++s) {
        if (s + 1 < NS) asm volatile("s_waitcnt vmcnt(8)" ::: "memory");
        else            asm volatile("s_waitcnt vmcnt(0)" ::: "memory");
        __builtin_amdgcn_sched_barrier(0);
        __builtin_amdgcn_s_barrier();          // buf[s%3] staged by ALL threads
        __builtin_amdgcn_sched_barrier(0);

        const int cur = s % 3;
        bf16x8 af[2][4], bf[2][4];
#pragma unroll
        for (int kc = 0; kc < 2; ++kc) {
            const int cs = (kc * 4 + l4) ^ (l15 & 7);   // r&7 == l15&7
#pragma unroll
            for (int m = 0; m < 4; ++m) {
                int r = wr * 64 + m * 16 + l15;
                af[kc][m] = *(const bf16x8*)(&abuf[cur][r * 128 + cs * 16]);
            }
#pragma unroll
            for (int n = 0; n < 4; ++n) {
                int r = wc * 64 + n * 16 + l15;
                bf[kc][n] = *(const bf16x8*)(&bbuf[cur][r * 128 + cs * 16]);
            }
        }

        if (s + 2 < NS) STAGE((s + 2) % 3, s + 2);   // flies under MFMA

        __builtin_amdgcn_s_setprio(1);
#pragma unroll
        for (int kc = 0; kc < 2; ++kc)
#pragma unroll
        for (int m = 0; m < 4; ++m)
#pragma unroll
        for (int n = 0; n < 4; ++n)
            acc[m][n] = __builtin_amdgcn_mfma_f32_16x16x32_bf16(
                af[kc][m], bf[kc][n], acc[m][n], 0, 0, 0);
        __builtin_amdgcn_s_setprio(0);
        asm volatile("s_waitcnt lgkmcnt(0)" ::: "memory");  // reads consumed
        __builtin_amdgcn_sched_barrier(0);
    }
#undef STAGE

    // ---- epilogue: partial logsumexp over this block's 128 cols ----
#pragma unroll
    for (int m = 0; m < 4; ++m) {
#pragma unroll
        for (int r = 0; r < 4; ++r) {
            const int lrow = wr * 64 + m * 16 + l4 * 4 + r;   // local row
            float lg[4];
            float mx = -1e30f;
#pragma unroll
            for (int n = 0; n < 4; ++n) {
                lg[n] = acc[m][n][r] * 5.0f;                  // /TEMP
                mx = fmaxf(mx, lg[n]);
            }
            mx = fmaxf(mx, __shfl_xor(mx, 1));
            mx = fmaxf(mx, __shfl_xor(mx, 2));
            mx = fmaxf(mx, __shfl_xor(mx, 4));
            mx = fmaxf(mx, __shfl_xor(mx, 8));
            float se = 0.f;
#pragma unroll
            for (int n = 0; n < 4; ++n) se += __expf(lg[n] - mx);
            se += __shfl_xor(se, 1);
            se += __shfl_xor(se, 2);
            se += __shfl_xor(se, 4);
            se += __shfl_xor(se, 8);
            if (l15 == 0) { sm_max[lrow][wc] = mx; sm_sum[lrow][wc] = se; }
            const int posc = (brow + lrow) & (NB - 1);        // global row % 512
#pragma unroll
            for (int n = 0; n < 4; ++n)
                if (bcol + wc * 64 + n * 16 + l15 == posc) sm_pos[lrow] = lg[n];
        }
    }
    __syncthreads();

    if (tid < BM) {
        const int lrow = tid;
        const int grow = brow + lrow;
        const float m0 = sm_max[lrow][0], m1 = sm_max[lrow][1];
        const float gm = fmaxf(m0, m1);
        const float tot = sm_sum[lrow][0] * __expf(m0 - gm)
                        + sm_sum[lrow][1] * __expf(m1 - gm);
        pmax_g[cb * NM + grow] = gm;
        psum_g[cb * NM + grow] = tot;
        if (((grow & (NB - 1)) >> 7) == cb) ppos_g[grow] = sm_pos[lrow];
    }
}

// ---------------------------------------------------------------------------
// Combine 4 col-block partials per row -> per-row loss term -> atomic sum.
__global__ __launch_bounds__(256) void reduce_kernel(
        const float* __restrict__ pmax_g, const float* __restrict__ psum_g,
        const float* __restrict__ ppos_g, float* __restrict__ loss_acc) {
    const int row = blockIdx.x * 256 + threadIdx.x;   // 32 blocks x 256
    const float m0 = pmax_g[row],          m1 = pmax_g[NM + row];
    const float m2 = pmax_g[2 * NM + row], m3 = pmax_g[3 * NM + row];
    const float gm = fmaxf(fmaxf(m0, m1), fmaxf(m2, m3));
    const float tot = psum_g[row]          * __expf(m0 - gm)
                    + psum_g[NM + row]     * __expf(m1 - gm)
                    + psum_g[2 * NM + row] * __expf(m2 - gm)
                    + psum_g[3 * NM + row] * __expf(m3 - gm);
    float term = gm + __logf(tot) - ppos_g[row];
#pragma unroll
    for (int off = 32; off > 0; off >>= 1) term += __shfl_xor(term, off);
    __shared__ float wsum[4];
    const int lane = threadIdx.x & 63, wv = threadIdx.x >> 6;
    if (lane == 0) wsum[wv] = term;
    __syncthreads();
    if (threadIdx.x == 0)
        atomicAdd(loss_acc, wsum[0] + wsum[1] + wsum[2] + wsum[3]);
}

__global__ void finalize_kernel(const float* __restrict__ acc,
                                float* __restrict__ out) {
    out[0] = acc[0] * (1.0f / (float)NM);
}

extern "C" void kernel_launch(void* const* d_in, const int* in_sizes, int n_in,
                              void* d_out, int out_size, void* d_ws, size_t ws_size,
                              hipStream_t stream) {
    const float* feat = (const float*)d_in[0];

    unsigned short* an = (unsigned short*)d_ws;            // 32 MB
    unsigned short* zn = an + (size_t)NM * ND;             // 2 MB
    float* lacc = (float*)(zn + (size_t)NB * ND);          // 1 float
    float* pmax = lacc + 1;                                // 4*NM
    float* psum = pmax + 4 * NM;                           // 4*NM
    float* ppos = psum + 4 * NM;                           // NM

    hipMemsetAsync(lacc, 0, sizeof(float), stream);

    prep_kernel<<<NB, 256, 0, stream>>>(feat, an, zn);
    gemm_loss_kernel<<<(NM / BM) * 4, 256, 0, stream>>>(an, zn, pmax, psum, ppos);
    reduce_kernel<<<NM / 256, 256, 0, stream>>>(pmax, psum, ppos, lacc);
    finalize_kernel<<<1, 1, 0, stream>>>(lacc, (float*)d_out);
}